// Round 4
// baseline (2977.225 us; speedup 1.0000x reference)
//
#include <hip/hip_runtime.h>
#include <stdint.h>

constexpr int kN = 50000;   // nodes
constexpr int kE = 800000;  // edges
constexpr int kD = 64;      // feature dim

__device__ __forceinline__ float bf2f(uint16_t u) {
    union { uint32_t i; float f; } v; v.i = ((uint32_t)u) << 16; return v.f;
}
__device__ __forceinline__ uint16_t f2bf(float f) {
    union { float ff; uint32_t i; } v; v.ff = f;
    return (uint16_t)((v.i + 0x7FFFu + ((v.i >> 16) & 1u)) >> 16); // RNE
}
__device__ __forceinline__ float wsum(float x) {
    x += __shfl_xor(x, 1);  x += __shfl_xor(x, 2);  x += __shfl_xor(x, 4);
    x += __shfl_xor(x, 8);  x += __shfl_xor(x, 16); x += __shfl_xor(x, 32);
    return x;  // butterfly: all 64 lanes end with the sum
}

// dtype-generic scalar load/store: BF=1 -> bf16 (u16<<16), BF=0 -> float32
template<int BF> __device__ __forceinline__ float ldf(const void* p, int i) {
    if (BF) return bf2f(((const uint16_t*)p)[i]);
    return ((const float*)p)[i];
}
template<int BF> __device__ __forceinline__ void stf(void* p, int i, float v) {
    if (BF) ((uint16_t*)p)[i] = f2bf(v);
    else    ((float*)p)[i] = v;
}
// vectorized 64-element row load into fp32 registers
template<int BF> __device__ __forceinline__ void ldrow64(const void* p, int base, float* v) {
    if (BF) {
        const uint4* q = (const uint4*)((const uint16_t*)p + base);  // rows are 128B, 16B-aligned
#pragma unroll
        for (int i = 0; i < 8; ++i) {
            uint4 u = q[i];
            v[8*i+0] = bf2f((uint16_t)u.x); v[8*i+1] = bf2f((uint16_t)(u.x >> 16));
            v[8*i+2] = bf2f((uint16_t)u.y); v[8*i+3] = bf2f((uint16_t)(u.y >> 16));
            v[8*i+4] = bf2f((uint16_t)u.z); v[8*i+5] = bf2f((uint16_t)(u.z >> 16));
            v[8*i+6] = bf2f((uint16_t)u.w); v[8*i+7] = bf2f((uint16_t)(u.w >> 16));
        }
    } else {
        const float4* q = (const float4*)((const float*)p + base);
#pragma unroll
        for (int i = 0; i < 16; ++i) {
            float4 f = q[i];
            v[4*i] = f.x; v[4*i+1] = f.y; v[4*i+2] = f.z; v[4*i+3] = f.w;
        }
    }
}
// dot(weight_row[rowbase..rowbase+64), v) — row address is wave-uniform -> s_load broadcast
template<int BF> __device__ __forceinline__ float dot64(const void* w, int rowbase, const float* v) {
    float a0 = 0.f, a1 = 0.f, a2 = 0.f, a3 = 0.f;
    if (BF) {
        const uint32_t* p = (const uint32_t*)w + (rowbase >> 1);
#pragma unroll
        for (int k = 0; k < 32; k += 2) {
            uint32_t ua = p[k], ub = p[k+1];
            a0 += bf2f((uint16_t)ua)         * v[2*k+0];
            a1 += bf2f((uint16_t)(ua >> 16)) * v[2*k+1];
            a2 += bf2f((uint16_t)ub)         * v[2*k+2];
            a3 += bf2f((uint16_t)(ub >> 16)) * v[2*k+3];
        }
    } else {
        const float* p = (const float*)w + rowbase;
#pragma unroll
        for (int k = 0; k < 64; k += 4) {
            a0 += p[k+0] * v[k+0];
            a1 += p[k+1] * v[k+1];
            a2 += p[k+2] * v[k+2];
            a3 += p[k+3] * v[k+3];
        }
    }
    return (a0 + a1) + (a2 + a3);
}

// K0: dtype probe. fp32 N(0,1) bytes viewed as bf16 produce wild exponents/NaN; bf16 N(0,1) never.
__global__ void k_detect(const uint16_t* __restrict__ nbr, int* __restrict__ flag) {
    int lane = threadIdx.x;  // 64 threads, 1 block
    float an = 0.f;
    for (int i = lane; i < 512; i += 64) {
        uint16_t u = nbr[i];
        if ((u & 0x7fffu) != 0) {           // skip +-0
            float a = fabsf(bf2f(u));
            if (!(a >= 1e-8f && a <= 1e8f)) an += 1.f;  // catches huge/denormal/NaN
        }
    }
    an = wsum(an);
    if (lane == 0) flag[0] = (an > 0.5f) ? 0 : 1;  // anomalies -> fp32(0), else bf16(1)
}

// K1: row_ptr[n] = lower_bound(batch_index, n) (sorted index -> CSR), row_ptr[kN] = kE
__global__ void k_rowptr(const int* __restrict__ bi, int* __restrict__ rp) {
    int n = blockIdx.x * 256 + threadIdx.x;
    if (n > kN) return;
    int lo = 0, hi = kE;
    while (lo < hi) { int mid = (lo + hi) >> 1; if (bi[mid] < n) lo = mid + 1; else hi = mid; }
    rp[n] = lo;
}

// K2: one wave per node, lane = dim. Online-softmax over the node's contiguous edge range.
// Single pass over nbr. weighted[n][:] = sum_e attn_e * nbr_e (bf16), fhas[n] = has-edges.
template<int BF>
__device__ __forceinline__ void edges_body(
    const void* node_emb, const void* nbr, const void* align_w, const void* align_b,
    const int* rp, uint16_t* weighted, float* fhas)
{
    const int lane = threadIdx.x & 63;
    const int n = blockIdx.x * 4 + (threadIdx.x >> 6);   // grid = kN/4 exactly
    float aw2 = ldf<BF>(align_w, kD + lane);
    float nd  = wsum(ldf<BF>(node_emb, n * kD + lane) * ldf<BF>(align_w, lane))
              + ldf<BF>(align_b, 0);                     // node part of score + bias
    const int s0 = rp[n], s1 = rp[n + 1];
    float m = -1e30f, l = 0.f, acc = 0.f;
    for (int e = s0; e < s1; ++e) {
        float v = ldf<BF>(nbr, e * kD + lane);           // coalesced 128/256B per wave
        float s = wsum(v * aw2) + nd;
        s = (s > 0.f) ? s : 0.01f * s;                   // leaky_relu(0.01)
        float mn = fmaxf(m, s);
        float al = __expf(m - mn);                       // first iter: exp(-big)=0
        float p  = __expf(s - mn);
        l   = l   * al + p;
        acc = acc * al + p * v;
        m = mn;
    }
    float w = (s1 > s0) ? (acc / l) : 0.f;               // l >= 1 when non-empty
    weighted[n * kD + lane] = f2bf(w);
    if (lane == 0) fhas[n] = (s1 > s0) ? 1.f : 0.f;
}
__global__ void k_edges(const void* node_emb, const void* nbr, const void* aw, const void* ab,
                        const int* __restrict__ rp, const int* __restrict__ flag,
                        uint16_t* __restrict__ weighted, float* __restrict__ fhas)
{
    if (*flag) edges_body<1>(node_emb, nbr, aw, ab, rp, weighted, fhas);
    else       edges_body<0>(node_emb, nbr, aw, ab, rp, weighted, fhas);
}

// K3: VALU GRU. Block = 256 = 4 waves over 64 nodes; lane -> node, wave -> 16 of the 64 output dims.
// Weight rows are wave-uniform -> compiler emits s_load (SGPR broadcast, no gather).
// ctx = elu(ctx_w·x + has*ctx_b) exchanged across waves via LDS (bf16); then torch-GRU gates.
template<int BF>
__device__ __forceinline__ void gru_body(
    const void* node_emb, const void* ctx_w, const void* ctx_b,
    const void* w_ih, const void* w_hh, const void* b_ih, const void* b_hh,
    const uint16_t* weighted, const float* fhas, void* out,
    uint16_t cl[64][66])
{
    const int lane = threadIdx.x & 63;
    const int wq   = threadIdx.x >> 6;       // 0..3: which 16-dim output slice
    const int node = blockIdx.x * 64 + lane;
    const bool live = (node < kN);
    const int nn = live ? node : (kN - 1);

    float x[kD];
    ldrow64<1>(weighted, nn * kD, x);        // internal buffer always bf16
    float has = fhas[nn];

    for (int jj = 0; jj < 16; ++jj) {        // my 16 ctx dims
        int j = wq * 16 + jj;
        float a = dot64<BF>(ctx_w, j * kD, x) + has * ldf<BF>(ctx_b, j);
        cl[lane][j] = f2bf((a > 0.f) ? a : (__expf(a) - 1.f));   // elu
    }
    __syncthreads();

    float c[kD], h[kD];
    {   // read back full ctx (LDS rows 4B-aligned: 66*2B=132)
        const uint32_t* cr = (const uint32_t*)&cl[lane][0];
#pragma unroll
        for (int i = 0; i < 32; ++i) {
            uint32_t u = cr[i];
            c[2*i] = bf2f((uint16_t)u); c[2*i+1] = bf2f((uint16_t)(u >> 16));
        }
    }
    ldrow64<BF>(node_emb, nn * kD, h);

    for (int jj = 0; jj < 16; ++jj) {        // my 16 output dims; torch gate order (r,z,n)
        int j = wq * 16 + jj;
        float ir = dot64<BF>(w_ih, j * kD, c)          + ldf<BF>(b_ih, j);
        float hr = dot64<BF>(w_hh, j * kD, h)          + ldf<BF>(b_hh, j);
        float iz = dot64<BF>(w_ih, (64 + j) * kD, c)   + ldf<BF>(b_ih, 64 + j);
        float hz = dot64<BF>(w_hh, (64 + j) * kD, h)   + ldf<BF>(b_hh, 64 + j);
        float in_ = dot64<BF>(w_ih, (128 + j) * kD, c) + ldf<BF>(b_ih, 128 + j);
        float hn = dot64<BF>(w_hh, (128 + j) * kD, h)  + ldf<BF>(b_hh, 128 + j);
        float r = 1.f / (1.f + __expf(-(ir + hr)));
        float z = 1.f / (1.f + __expf(-(iz + hz)));
        float t = in_ + r * hn;
        float g = 2.f / (1.f + __expf(-2.f * t)) - 1.f;   // tanh
        float o = (1.f - z) * g + z * ldf<BF>(node_emb, nn * kD + j);
        if (live) stf<BF>(out, node * kD + j, fmaxf(o, 0.f));  // relu
    }
}
__global__ void k_gru(
    const void* node_emb, const void* ctx_w, const void* ctx_b,
    const void* w_ih, const void* w_hh, const void* b_ih, const void* b_hh,
    const uint16_t* __restrict__ weighted, const float* __restrict__ fhas,
    const int* __restrict__ flag, void* out)
{
    __shared__ uint16_t cl[64][66];  // +2 pad: bank = lane + i (conflict-free)
    if (*flag) gru_body<1>(node_emb, ctx_w, ctx_b, w_ih, w_hh, b_ih, b_hh, weighted, fhas, out, cl);
    else       gru_body<0>(node_emb, ctx_w, ctx_b, w_ih, w_hh, b_ih, b_hh, weighted, fhas, out, cl);
}

extern "C" void kernel_launch(void* const* d_in, const int* in_sizes, int n_in,
                              void* d_out, int out_size, void* d_ws, size_t ws_size,
                              hipStream_t stream) {
    (void)in_sizes; (void)n_in; (void)out_size; (void)ws_size;
    const void* node_emb = d_in[0];
    const void* nbr      = d_in[1];
    const int*  bi       = (const int*)d_in[2];
    const void* align_w  = d_in[3];
    const void* align_b  = d_in[4];
    const void* ctx_w    = d_in[5];
    const void* ctx_b    = d_in[6];
    const void* w_ih     = d_in[7];
    const void* w_hh     = d_in[8];
    const void* b_ih     = d_in[9];
    const void* b_hh     = d_in[10];

    // ws: [0,200004) row_ptr; flag @200064; fhas f32[kN] @204800; weighted bf16[kN*64] @409600 (~6.8 MB total)
    char* ws = (char*)d_ws;
    int*      row_ptr  = (int*)ws;
    int*      flag     = (int*)(ws + 200064);
    float*    fhas     = (float*)(ws + 204800);
    uint16_t* weighted = (uint16_t*)(ws + 409600);

    k_detect<<<1, 64, 0, stream>>>((const uint16_t*)nbr, flag);
    k_rowptr<<<(kN + 256) / 256, 256, 0, stream>>>(bi, row_ptr);
    k_edges<<<kN / 4, 256, 0, stream>>>(node_emb, nbr, align_w, align_b, row_ptr, flag, weighted, fhas);
    k_gru<<<(kN + 63) / 64, 256, 0, stream>>>(node_emb, ctx_w, ctx_b, w_ih, w_hh, b_ih, b_hh,
                                              weighted, fhas, flag, d_out);
}

// Round 5
// 383.400 us; speedup vs baseline: 7.7653x; 7.7653x over previous
//
#include <hip/hip_runtime.h>
#include <stdint.h>

constexpr int kN = 50000;   // nodes
constexpr int kE = 800000;  // edges
constexpr int kD = 64;      // feature dim

// MFMA fragment types — per guide's compile-verified example: short ext-vector carries bf16.
typedef short sv8 __attribute__((ext_vector_type(8)));   // 8 bf16 (4 VGPRs), A/B frag
typedef float fv4 __attribute__((ext_vector_type(4)));   // 4 fp32, C/D frag

__device__ __forceinline__ float bf2f(uint16_t u) {
    union { uint32_t i; float f; } v; v.i = ((uint32_t)u) << 16; return v.f;
}
__device__ __forceinline__ uint16_t f2bf(float f) {
    union { float ff; uint32_t i; } v; v.ff = f;
    return (uint16_t)((v.i + 0x7FFFu + ((v.i >> 16) & 1u)) >> 16); // RNE
}
__device__ __forceinline__ float wsum64(float x) {
    x += __shfl_xor(x, 1);  x += __shfl_xor(x, 2);  x += __shfl_xor(x, 4);
    x += __shfl_xor(x, 8);  x += __shfl_xor(x, 16); x += __shfl_xor(x, 32);
    return x;
}

template<int BF> __device__ __forceinline__ float ldf(const void* p, int i) {
    if (BF) return bf2f(((const uint16_t*)p)[i]);
    return ((const float*)p)[i];
}
template<int BF> __device__ __forceinline__ void stf(void* p, int i, float v) {
    if (BF) ((uint16_t*)p)[i] = f2bf(v);
    else    ((float*)p)[i] = v;
}
// 8 consecutive elements starting at elem_base -> bf16 MFMA frag (converts if fp32)
template<int BF> __device__ __forceinline__ sv8 ldfrag(const void* p, int elem_base) {
    if (BF) {
        return *(const sv8*)((const uint16_t*)p + elem_base);
    } else {
        const float* f = (const float*)p + elem_base;
        sv8 r;
#pragma unroll
        for (int i = 0; i < 8; ++i) r[i] = (short)f2bf(f[i]);
        return r;
    }
}
__device__ __forceinline__ fv4 mfma16(sv8 a, sv8 b, fv4 c) {
    return __builtin_amdgcn_mfma_f32_16x16x32_bf16(a, b, c, 0, 0, 0);
}

// K0: dtype probe. fp32 N(0,1) bytes viewed as bf16 give wild exponents/NaN; bf16 N(0,1) never.
__global__ void k_detect(const uint16_t* __restrict__ nbr, int* __restrict__ flag) {
    int lane = threadIdx.x;  // 64 threads, 1 block
    float an = 0.f;
    for (int i = lane; i < 512; i += 64) {
        uint16_t u = nbr[i];
        if ((u & 0x7fffu) != 0) {
            float a = fabsf(bf2f(u));
            if (!(a >= 1e-8f && a <= 1e8f)) an += 1.f;
        }
    }
    an = wsum64(an);
    if (lane == 0) flag[0] = (an > 0.5f) ? 0 : 1;  // anomalies -> fp32(0), else bf16(1)
}

// K1: row_ptr[n] = lower_bound(batch_index, n) (sorted index -> CSR), row_ptr[kN] = kE
__global__ void k_rowptr(const int* __restrict__ bi, int* __restrict__ rp) {
    int n = blockIdx.x * 256 + threadIdx.x;
    if (n > kN) return;
    int lo = 0, hi = kE;
    while (lo < hi) { int mid = (lo + hi) >> 1; if (bi[mid] < n) lo = mid + 1; else hi = mid; }
    rp[n] = lo;
}

// K2: one wave per node. Wave = 4 groups x 16 lanes; group g owns edges e0+g (stride 4),
// lane t of a group owns dims 4t..4t+3 (8B contiguous load). Independent online-softmax
// per group, merged at the end via xor-16/32 butterflies. Single pass over nbr.
template<int BF>
__device__ __forceinline__ void edges_body(
    const void* node_emb, const void* nbr, const void* align_w, const void* align_b,
    const int* rp, uint16_t* weighted, float* fhas)
{
    const int lane = threadIdx.x & 63;
    const int n    = blockIdx.x * 4 + (threadIdx.x >> 6);   // grid = kN/4 exactly
    const int g    = lane >> 4;     // edge group 0..3
    const int t    = lane & 15;     // dim quad 0..15

    // node part of the score (+ bias): full-wave dot, all lanes get it
    float nd = wsum64(ldf<BF>(node_emb, n * kD + lane) * ldf<BF>(align_w, lane))
             + ldf<BF>(align_b, 0);

    // my 4 weights of the neighbour half of align_w
    float w0 = ldf<BF>(align_w, kD + t * 4 + 0);
    float w1 = ldf<BF>(align_w, kD + t * 4 + 1);
    float w2 = ldf<BF>(align_w, kD + t * 4 + 2);
    float w3 = ldf<BF>(align_w, kD + t * 4 + 3);

    const int s0 = rp[n], s1 = rp[n + 1];
    float m = -1e30f, l = 0.f;
    float a0 = 0.f, a1 = 0.f, a2 = 0.f, a3 = 0.f;

    for (int eb = s0; eb < s1; eb += 4) {
        int e = eb + g;
        bool valid = (e < s1);
        int ec = valid ? e : s0;                     // safe addr (loop entered => s1 > s0)
        float v0, v1, v2, v3;
        if (BF) {
            uint2 u = *(const uint2*)((const uint16_t*)nbr + ec * kD + t * 4);
            v0 = bf2f((uint16_t)u.x); v1 = bf2f((uint16_t)(u.x >> 16));
            v2 = bf2f((uint16_t)u.y); v3 = bf2f((uint16_t)(u.y >> 16));
        } else {
            float4 f = *(const float4*)((const float*)nbr + ec * kD + t * 4);
            v0 = f.x; v1 = f.y; v2 = f.z; v3 = f.w;
        }
        float part = v0 * w0 + v1 * w1 + v2 * w2 + v3 * w3;
        part += __shfl_xor(part, 1);
        part += __shfl_xor(part, 2);
        part += __shfl_xor(part, 4);
        part += __shfl_xor(part, 8);                 // group-wide dot
        float s = part + nd;
        s = (s > 0.f) ? s : 0.01f * s;               // leaky_relu(0.01)
        s = valid ? s : -1e30f;
        float mn = fmaxf(m, s);
        float al = __expf(m - mn);
        float p  = valid ? __expf(s - mn) : 0.f;
        l  = l  * al + p;
        a0 = a0 * al + p * v0;
        a1 = a1 * al + p * v1;
        a2 = a2 * al + p * v2;
        a3 = a3 * al + p * v3;
        m = mn;
    }

    // merge the 4 groups: rescale to global max, butterfly-sum across lanes 16/32 apart
    float M = fmaxf(m, __shfl_xor(m, 16));
    M = fmaxf(M, __shfl_xor(M, 32));
    float sc = __expf(m - M);                        // 0 for empty groups (m=-1e30, M finite)
    l  *= sc;  a0 *= sc;  a1 *= sc;  a2 *= sc;  a3 *= sc;
    l  += __shfl_xor(l, 16);   l  += __shfl_xor(l, 32);
    a0 += __shfl_xor(a0, 16);  a0 += __shfl_xor(a0, 32);
    a1 += __shfl_xor(a1, 16);  a1 += __shfl_xor(a1, 32);
    a2 += __shfl_xor(a2, 16);  a2 += __shfl_xor(a2, 32);
    a3 += __shfl_xor(a3, 16);  a3 += __shfl_xor(a3, 32);

    if (g == 0) {
        float inv = (s1 > s0) ? (1.f / l) : 0.f;     // l >= 1 when non-empty
        uint32_t lo = (uint32_t)f2bf(a0 * inv) | ((uint32_t)f2bf(a1 * inv) << 16);
        uint32_t hi = (uint32_t)f2bf(a2 * inv) | ((uint32_t)f2bf(a3 * inv) << 16);
        *(uint2*)(weighted + n * kD + t * 4) = make_uint2(lo, hi);
        if (t == 0) fhas[n] = (s1 > s0) ? 1.f : 0.f;
    }
}
__global__ __launch_bounds__(256, 4) void k_edges(
    const void* node_emb, const void* nbr, const void* aw, const void* ab,
    const int* __restrict__ rp, const int* __restrict__ flag,
    uint16_t* __restrict__ weighted, float* __restrict__ fhas)
{
    if (*flag) edges_body<1>(node_emb, nbr, aw, ab, rp, weighted, fhas);
    else       edges_body<0>(node_emb, nbr, aw, ab, rp, weighted, fhas);
}

// K3: MFMA GEMM + GRU. Block=256 (4 waves), wave owns 16 node rows.
// ctx_pre = weighted @ ctx_w^T ; gh = node_emb @ w_hh^T ; ctx = elu(ctx_pre + has*ctx_b)
// gi = ctx @ w_ih^T ; torch gates (r,z,n); out = relu((1-z)*g + z*h).
// A layout: A[m=lane&15][k=(lane>>4)*8+j]; C/D: col=lane&15, row=(lane>>4)*4+reg.
template<int BF>
__device__ __forceinline__ void gru_body(
    const void* node_emb,
    const void* ctx_w, const void* ctx_b,
    const void* w_ih,  const void* w_hh,
    const void* b_ih,  const void* b_hh,
    const uint16_t* weighted, const float* fhas, void* out,
    uint16_t (*sctx)[16][80])
{
    const int lane = threadIdx.x & 63;
    const int wv   = threadIdx.x >> 6;
    const int R    = blockIdx.x * 64 + wv * 16;  // node row base for this wave
    const int t    = lane & 15;
    const int q    = lane >> 4;

    const fv4 zf = {0.f, 0.f, 0.f, 0.f};

    int ar = R + t; if (ar > kN - 1) ar = kN - 1;      // clamp (only fully-OOB tail waves)
    sv8 ah0 = ldfrag<BF>(node_emb, ar * kD + q * 8);
    sv8 ah1 = ldfrag<BF>(node_emb, ar * kD + q * 8 + 32);
    sv8 aw0 = ldfrag<1>(weighted, ar * kD + q * 8);    // internal buffer always bf16
    sv8 aw1 = ldfrag<1>(weighted, ar * kD + q * 8 + 32);

    fv4 accC[4], accH[12];
#pragma unroll
    for (int i = 0; i < 4; ++i)  accC[i] = zf;
#pragma unroll
    for (int i = 0; i < 12; ++i) accH[i] = zf;

#pragma unroll
    for (int ct = 0; ct < 4; ++ct) {       // ctx_pre: 4 col-tiles of 16
        int rb = (ct * 16 + t) * kD + q * 8;
        accC[ct] = mfma16(aw0, ldfrag<BF>(ctx_w, rb),      accC[ct]);
        accC[ct] = mfma16(aw1, ldfrag<BF>(ctx_w, rb + 32), accC[ct]);
    }
#pragma unroll
    for (int ct = 0; ct < 12; ++ct) {      // gh: 12 col-tiles (r,z,n gates)
        int rb = (ct * 16 + t) * kD + q * 8;
        accH[ct] = mfma16(ah0, ldfrag<BF>(w_hh, rb),      accH[ct]);
        accH[ct] = mfma16(ah1, ldfrag<BF>(w_hh, rb + 32), accH[ct]);
    }

    // epilogue 1: ctx = elu(pre + has*ctx_b) -> bf16 -> sctx (C-layout -> row-major)
    float has_i[4];
#pragma unroll
    for (int i = 0; i < 4; ++i) {
        int node = R + q * 4 + i; if (node > kN - 1) node = kN - 1;
        has_i[i] = fhas[node];
    }
#pragma unroll
    for (int ct = 0; ct < 4; ++ct) {
        int col = ct * 16 + t;
        float cb = ldf<BF>(ctx_b, col);
#pragma unroll
        for (int i = 0; i < 4; ++i) {
            float x = accC[ct][i] + has_i[i] * cb;
            x = (x > 0.f) ? x : (__expf(x) - 1.f);     // elu
            sctx[wv][q * 4 + i][col] = f2bf(x);
        }
    }
    __syncthreads();  // all waves reach this (no early returns)

    sv8 ac0 = *(const sv8*)&sctx[wv][t][q * 8];
    sv8 ac1 = *(const sv8*)&sctx[wv][t][q * 8 + 32];

    fv4 accI[12];
#pragma unroll
    for (int i = 0; i < 12; ++i) accI[i] = zf;
#pragma unroll
    for (int ct = 0; ct < 12; ++ct) {      // gi = ctx @ w_ih^T
        int rb = (ct * 16 + t) * kD + q * 8;
        accI[ct] = mfma16(ac0, ldfrag<BF>(w_ih, rb),      accI[ct]);
        accI[ct] = mfma16(ac1, ldfrag<BF>(w_ih, rb + 32), accI[ct]);
    }

    // epilogue 2: GRU gates + relu, store
#pragma unroll
    for (int jt = 0; jt < 4; ++jt) {
        int col = jt * 16 + t;
        float bir = ldf<BF>(b_ih, col),       bhr = ldf<BF>(b_hh, col);
        float biz = ldf<BF>(b_ih, 64 + col),  bhz = ldf<BF>(b_hh, 64 + col);
        float bin = ldf<BF>(b_ih, 128 + col), bhn = ldf<BF>(b_hh, 128 + col);
#pragma unroll
        for (int i = 0; i < 4; ++i) {
            int node = R + q * 4 + i;
            bool valid = node < kN;
            int cn = valid ? node : kN - 1;
            float hv = ldf<BF>(node_emb, cn * kD + col);
            float r = 1.f / (1.f + __expf(-(accI[jt][i]     + bir + accH[jt][i]     + bhr)));
            float z = 1.f / (1.f + __expf(-(accI[jt + 4][i] + biz + accH[jt + 4][i] + bhz)));
            float tt = accI[jt + 8][i] + bin + r * (accH[jt + 8][i] + bhn);
            float gg = 2.f / (1.f + __expf(-2.f * tt)) - 1.f;   // tanh
            float hn = (1.f - z) * gg + z * hv;
            if (valid) stf<BF>(out, node * kD + col, fmaxf(hn, 0.f));  // relu
        }
    }
}
__global__ __launch_bounds__(256, 2) void k_gru(
    const void* node_emb, const void* ctx_w, const void* ctx_b,
    const void* w_ih, const void* w_hh, const void* b_ih, const void* b_hh,
    const uint16_t* __restrict__ weighted, const float* __restrict__ fhas,
    const int* __restrict__ flag, void* out)
{
    __shared__ uint16_t sctx[4][16][80];  // per-wave ctx C->A transpose buffer (10.2 KB)
    if (*flag) gru_body<1>(node_emb, ctx_w, ctx_b, w_ih, w_hh, b_ih, b_hh, weighted, fhas, out, sctx);
    else       gru_body<0>(node_emb, ctx_w, ctx_b, w_ih, w_hh, b_ih, b_hh, weighted, fhas, out, sctx);
}

extern "C" void kernel_launch(void* const* d_in, const int* in_sizes, int n_in,
                              void* d_out, int out_size, void* d_ws, size_t ws_size,
                              hipStream_t stream) {
    (void)in_sizes; (void)n_in; (void)out_size; (void)ws_size;
    const void* node_emb = d_in[0];
    const void* nbr      = d_in[1];
    const int*  bi       = (const int*)d_in[2];
    const void* align_w  = d_in[3];
    const void* align_b  = d_in[4];
    const void* ctx_w    = d_in[5];
    const void* ctx_b    = d_in[6];
    const void* w_ih     = d_in[7];
    const void* w_hh     = d_in[8];
    const void* b_ih     = d_in[9];
    const void* b_hh     = d_in[10];

    // ws: [0,200004) row_ptr; flag @200064; fhas f32[kN] @204800; weighted bf16[kN*64] @409600 (~6.8 MB)
    char* ws = (char*)d_ws;
    int*      row_ptr  = (int*)ws;
    int*      flag     = (int*)(ws + 200064);
    float*    fhas     = (float*)(ws + 204800);
    uint16_t* weighted = (uint16_t*)(ws + 409600);

    k_detect<<<1, 64, 0, stream>>>((const uint16_t*)nbr, flag);
    k_rowptr<<<(kN + 256) / 256, 256, 0, stream>>>(bi, row_ptr);
    k_edges<<<kN / 4, 256, 0, stream>>>(node_emb, nbr, align_w, align_b, row_ptr, flag, weighted, fhas);
    k_gru<<<(kN + 63) / 64, 256, 0, stream>>>(node_emb, ctx_w, ctx_b, w_ih, w_hh, b_ih, b_hh,
                                              weighted, fhas, flag, d_out);
}